// Round 2
// baseline (654.007 us; speedup 1.0000x reference)
//
#include <hip/hip_runtime.h>

// B=8, H=W=256, I_DIM=64, K_DIM=64 (hd_k=32), V_DIM=32 (hd_v=16), O_DIM=64
// NH=2, unfold: p=7, stride=21, dilation=4, npw=12 -> S=144 patches
// Sampled grid 84x84; each sampled pixel belongs to exactly ONE patch.
#define BB 8
#define HH 256
#define CIN 64
#define NPW 12
#define SPP 144
#define PP 49
#define PDIM 7
#define STRIDE 21
#define DIL 4
#define NS 84
#define HDK 32
#define HDV 16
#define ASTR 53                     // A1/A2 row stride (breaks 4*stride%32 power-of-2 banks)
#define PSTR (8LL*64*84*84)         // per-head stride in P (floats)

// ---------------------------------------------------------------------------
// Kernel 1: one block per (b, patch, head). Gather x1/x2, project K1/K2/V1/V2
// for this head, 49x49 dual softmax attention, then PARTIAL output projection
// (this head's 32 channels through Wp) written to P[n][b][oc][84][84].
// ---------------------------------------------------------------------------
__global__ __launch_bounds__(256, 3) void k1_fused(
    const float* __restrict__ x1, const float* __restrict__ x2,
    const float* __restrict__ Wk, const float* __restrict__ bk,
    const float* __restrict__ Wv, const float* __restrict__ bv,
    const float* __restrict__ Wp, float* __restrict__ P)
{
  // kv rows: 0..31 K1(head n), 32..63 K2, 64..79 V1, 80..95 V2
  __shared__ float kv[96][50];
  __shared__ union UU {
    float xs[2][CIN][50];                           // phases 0-1
    struct {                                        // phases 2+
      float A1[49][ASTR];
      float A2[49][ASTR];
      float rmax[49], rsum[49], cmax[49], csum[49];
    } a;
  } u;
  __shared__ float O[32][50];  // rows 0..15 = o1(d), 16..31 = o2(d)

  const int tid = threadIdx.x;
  // decode so that the two heads of one patch land on the same XCD (blk%8):
  // id = (pairHi<<4) | (n<<3) | pairLo
  const int id = blockIdx.x;
  const int n = (id >> 3) & 1;
  const int pair = (id & 7) | ((id >> 4) << 3);     // 0..1151
  const int b = pair / SPP, s = pair % SPP;
  const int pi = s / NPW, pj = s % NPW;
  const int h0 = pi * STRIDE, w0 = pj * STRIDE;

  // ---- phase 0: gather x tiles into LDS ----
  for (int i = tid; i < 2 * CIN * PP; i += 256) {
    int src = i / (CIN * PP);
    int r = i - src * (CIN * PP);
    int c = r / PP, t = r - c * PP;
    int ph = t / PDIM, pw = t - ph * PDIM;
    const float* xp = src ? x2 : x1;
    u.xs[src][c][t] =
        xp[(((size_t)b * CIN + c) * HH + (h0 + ph * DIL)) * HH + (w0 + pw * DIL)];
  }
  __syncthreads();

  // ---- phase 1: projections for this head: 96 rows x 49 px, 4x4 tiles ----
  for (int task = tid; task < 24 * 13; task += 256) {
    int g = task / 13, tg = task % 13;
    int row0 = g * 4, t0 = tg * 4;
    int tc[4];
    #pragma unroll
    for (int j = 0; j < 4; j++) tc[j] = min(t0 + j, PP - 1);
    int src;
    const float* wbase;
    float bias[4];
    if (row0 < 32) {
      src = 0; wbase = Wk + (n * HDK + row0) * 64;
      #pragma unroll
      for (int i = 0; i < 4; i++) bias[i] = bk[n * HDK + row0 + i];
    } else if (row0 < 64) {
      src = 1; wbase = Wk + (64 + n * HDK + (row0 - 32)) * 64;
      #pragma unroll
      for (int i = 0; i < 4; i++) bias[i] = bk[64 + n * HDK + (row0 - 32) + i];
    } else if (row0 < 80) {
      src = 0; wbase = Wv + (n * HDV + (row0 - 64)) * 64;
      #pragma unroll
      for (int i = 0; i < 4; i++) bias[i] = bv[n * HDV + (row0 - 64) + i];
    } else {
      src = 1; wbase = Wv + (32 + n * HDV + (row0 - 80)) * 64;
      #pragma unroll
      for (int i = 0; i < 4; i++) bias[i] = bv[32 + n * HDV + (row0 - 80) + i];
    }
    const float* xsrc = &u.xs[src][0][0];
    float acc[4][4];
    #pragma unroll
    for (int i = 0; i < 4; i++)
      #pragma unroll
      for (int j = 0; j < 4; j++) acc[i][j] = 0.f;
    for (int c = 0; c < 64; c++) {
      float wv0 = wbase[c], wv1 = wbase[64 + c], wv2 = wbase[128 + c], wv3 = wbase[192 + c];
      #pragma unroll
      for (int j = 0; j < 4; j++) {
        float xv = xsrc[c * 50 + tc[j]];
        acc[0][j] += wv0 * xv; acc[1][j] += wv1 * xv;
        acc[2][j] += wv2 * xv; acc[3][j] += wv3 * xv;
      }
    }
    #pragma unroll
    for (int i = 0; i < 4; i++)
      #pragma unroll
      for (int j = 0; j < 4; j++)
        if (t0 + j < PP) kv[row0 + i][t0 + j] = acc[i][j] + bias[i];
  }
  __syncthreads();  // xs dead; union becomes A1/A2

  const float scale = 0.17677669529663687f;  // 1/sqrt(32)

  // ---- phase 2: kk[x][y] = scale * sum_d K1[d][x]*K2[d][y] ----
  for (int task = tid; task < 13 * 13; task += 256) {
    int xg = task / 13, yg = task % 13;
    int x0 = xg * 4, y0 = yg * 4;
    int xc[4], yc[4];
    #pragma unroll
    for (int j = 0; j < 4; j++) { xc[j] = min(x0 + j, 48); yc[j] = min(y0 + j, 48); }
    float acc[4][4];
    #pragma unroll
    for (int i = 0; i < 4; i++)
      #pragma unroll
      for (int j = 0; j < 4; j++) acc[i][j] = 0.f;
    for (int d = 0; d < HDK; d++) {
      const float* k1r = kv[d];
      const float* k2r = kv[32 + d];
      float a0 = k1r[xc[0]], a1v = k1r[xc[1]], a2v = k1r[xc[2]], a3v = k1r[xc[3]];
      float b0 = k2r[yc[0]], b1v = k2r[yc[1]], b2v = k2r[yc[2]], b3v = k2r[yc[3]];
      acc[0][0] += a0 * b0;  acc[0][1] += a0 * b1v;  acc[0][2] += a0 * b2v;  acc[0][3] += a0 * b3v;
      acc[1][0] += a1v * b0; acc[1][1] += a1v * b1v; acc[1][2] += a1v * b2v; acc[1][3] += a1v * b3v;
      acc[2][0] += a2v * b0; acc[2][1] += a2v * b1v; acc[2][2] += a2v * b2v; acc[2][3] += a2v * b3v;
      acc[3][0] += a3v * b0; acc[3][1] += a3v * b1v; acc[3][2] += a3v * b2v; acc[3][3] += a3v * b3v;
    }
    #pragma unroll
    for (int i = 0; i < 4; i++)
      if (x0 + i < 49)
        #pragma unroll
        for (int j = 0; j < 4; j++)
          if (y0 + j < 49) u.a.A1[x0 + i][y0 + j] = acc[i][j] * scale;
  }
  __syncthreads();

  // ---- phase 3: softmax stats (cols for a1, rows for a2) ----
  if (tid < 98) {
    int isRow = tid >= 49;
    int j = tid - (isRow ? 49 : 0);
    float m = -1e30f;
    for (int k = 0; k < 49; k++) {
      float v = isRow ? u.a.A1[j][k] : u.a.A1[k][j];
      m = fmaxf(m, v);
    }
    float sm = 0.f;
    for (int k = 0; k < 49; k++) {
      float v = isRow ? u.a.A1[j][k] : u.a.A1[k][j];
      sm += __expf(v - m);
    }
    if (isRow) { u.a.rmax[j] = m; u.a.rsum[j] = 1.0f / sm; }
    else       { u.a.cmax[j] = m; u.a.csum[j] = 1.0f / sm; }
  }
  __syncthreads();

  // ---- phase 4: A2 = row softmax, A1 = col softmax (in place) ----
  for (int i = tid; i < 49 * 49; i += 256) {
    int x = i / 49, y = i - x * 49;
    float v = u.a.A1[x][y];
    u.a.A2[x][y] = __expf(v - u.a.rmax[x]) * u.a.rsum[x];
    u.a.A1[x][y] = __expf(v - u.a.cmax[y]) * u.a.csum[y];
  }
  __syncthreads();

  // ---- phase 5: o1[d][y] = sum_x A1[x][y]*V1[d][x]; o2[d][x] = sum_y A2[x][y]*V2[d][y]
  for (int task = tid; task < 2 * 4 * 13; task += 256) {
    int which = task / 52;
    int r = task - which * 52;
    int dg = r / 13, tg = r % 13;
    int d0 = dg * 4, t0 = tg * 4;
    int tc[4];
    #pragma unroll
    for (int j = 0; j < 4; j++) tc[j] = min(t0 + j, 48);
    float acc[4][4];
    #pragma unroll
    for (int i = 0; i < 4; i++)
      #pragma unroll
      for (int j = 0; j < 4; j++) acc[i][j] = 0.f;
    if (which == 0) {
      for (int x = 0; x < 49; x++) {
        float a0 = u.a.A1[x][tc[0]], a1v = u.a.A1[x][tc[1]];
        float a2v = u.a.A1[x][tc[2]], a3v = u.a.A1[x][tc[3]];
        #pragma unroll
        for (int i = 0; i < 4; i++) {
          float vv = kv[64 + d0 + i][x];
          acc[i][0] += vv * a0; acc[i][1] += vv * a1v;
          acc[i][2] += vv * a2v; acc[i][3] += vv * a3v;
        }
      }
    } else {
      for (int y = 0; y < 49; y++) {
        float a0 = u.a.A2[tc[0]][y], a1v = u.a.A2[tc[1]][y];
        float a2v = u.a.A2[tc[2]][y], a3v = u.a.A2[tc[3]][y];
        #pragma unroll
        for (int i = 0; i < 4; i++) {
          float vv = kv[80 + d0 + i][y];
          acc[i][0] += vv * a0; acc[i][1] += vv * a1v;
          acc[i][2] += vv * a2v; acc[i][3] += vv * a3v;
        }
      }
    }
    #pragma unroll
    for (int i = 0; i < 4; i++)
      #pragma unroll
      for (int j = 0; j < 4; j++)
        if (t0 + j < 49) O[which * 16 + d0 + i][t0 + j] = acc[i][j];
  }
  __syncthreads();

  // ---- phase 6: partial out-proj. P_n[oc][pos] = sum_l Wp[oc][ch(l)] * O[l][pos]
  // ch(l) = l<16 ? n*16+l : 16+n*16+l   (o2 channels are 32+n*16+(l-16))
  for (int task = tid; task < 16 * 13; task += 256) {
    int ocg = task / 13, tg = task % 13;
    int oc0 = ocg * 4, t0 = tg * 4;
    int tc[4];
    #pragma unroll
    for (int j = 0; j < 4; j++) tc[j] = min(t0 + j, 48);
    float acc[4][4];
    #pragma unroll
    for (int i = 0; i < 4; i++)
      #pragma unroll
      for (int j = 0; j < 4; j++) acc[i][j] = 0.f;
    #pragma unroll 4
    for (int l = 0; l < 32; l++) {
      int ch = (l < 16) ? (n * HDV + l) : (16 + n * HDV + l);
      float w0 = Wp[(oc0 + 0) * 64 + ch];
      float w1 = Wp[(oc0 + 1) * 64 + ch];
      float w2 = Wp[(oc0 + 2) * 64 + ch];
      float w3 = Wp[(oc0 + 3) * 64 + ch];
      float o0 = O[l][tc[0]], o1v = O[l][tc[1]], o2v = O[l][tc[2]], o3v = O[l][tc[3]];
      acc[0][0] += w0 * o0; acc[0][1] += w0 * o1v; acc[0][2] += w0 * o2v; acc[0][3] += w0 * o3v;
      acc[1][0] += w1 * o0; acc[1][1] += w1 * o1v; acc[1][2] += w1 * o2v; acc[1][3] += w1 * o3v;
      acc[2][0] += w2 * o0; acc[2][1] += w2 * o1v; acc[2][2] += w2 * o2v; acc[2][3] += w2 * o3v;
      acc[3][0] += w3 * o0; acc[3][1] += w3 * o1v; acc[3][2] += w3 * o2v; acc[3][3] += w3 * o3v;
    }
    #pragma unroll
    for (int i = 0; i < 4; i++) {
      #pragma unroll
      for (int j = 0; j < 4; j++) {
        int t = t0 + j;
        if (t < 49) {
          int ph = t / 7, pw = t - ph * 7;
          P[(size_t)n * PSTR +
            (((size_t)b * 64 + (oc0 + i)) * NS + (pi * 7 + ph)) * NS + (pj * 7 + pw)] =
              acc[i][j];
        }
      }
    }
  }
}

// ---------------------------------------------------------------------------
// Kernel 2: merge. out[b][oc][h][w] = bp[oc] + (sampled ? P0+P1 : 0).
// One block per (b,h); float4 stores.
// ---------------------------------------------------------------------------
__global__ __launch_bounds__(256) void k2_merge(
    const float* __restrict__ P, const float* __restrict__ bp,
    float* __restrict__ out)
{
  __shared__ float bps[64];
  __shared__ int wsmap[256];
  const int tid = threadIdx.x;
  const int b = blockIdx.x / HH, h = blockIdx.x % HH;
  if (tid < 64) bps[tid] = bp[tid];
  {
    int w = tid, wsv = -1;
    for (int pj = 0; pj < NPW; pj++) {
      int r = w - pj * STRIDE;
      if (r >= 0 && r <= (PDIM - 1) * DIL && (r % DIL) == 0) { wsv = pj * PDIM + r / DIL; break; }
    }
    wsmap[tid] = wsv;
  }
  int hs = -1;
  for (int pi = 0; pi < NPW; pi++) {
    int r = h - pi * STRIDE;
    if (r >= 0 && r <= (PDIM - 1) * DIL && (r % DIL) == 0) { hs = pi * PDIM + r / DIL; break; }
  }
  __syncthreads();

  const int wq = tid & 63;   // float4 column
  const int ocq = tid >> 6;  // 0..3
  float4* out4 = (float4*)out;

  if (hs < 0) {
    for (int oc = ocq; oc < 64; oc += 4) {
      float bv = bps[oc];
      out4[(((size_t)b * 64 + oc) * HH + h) * 64 + wq] = make_float4(bv, bv, bv, bv);
    }
    return;
  }
  const int ws0 = wsmap[wq * 4 + 0], ws1 = wsmap[wq * 4 + 1];
  const int ws2 = wsmap[wq * 4 + 2], ws3 = wsmap[wq * 4 + 3];
  for (int oc = ocq; oc < 64; oc += 4) {
    float bv = bps[oc];
    size_t rbase = (((size_t)b * 64 + oc) * NS + hs) * NS;
    float4 v = make_float4(bv, bv, bv, bv);
    if (ws0 >= 0) v.x += P[rbase + ws0] + P[PSTR + rbase + ws0];
    if (ws1 >= 0) v.y += P[rbase + ws1] + P[PSTR + rbase + ws1];
    if (ws2 >= 0) v.z += P[rbase + ws2] + P[PSTR + rbase + ws2];
    if (ws3 >= 0) v.w += P[rbase + ws3] + P[PSTR + rbase + ws3];
    out4[(((size_t)b * 64 + oc) * HH + h) * 64 + wq] = v;
  }
}

extern "C" void kernel_launch(void* const* d_in, const int* in_sizes, int n_in,
                              void* d_out, int out_size, void* d_ws, size_t ws_size,
                              hipStream_t stream) {
  const float* x1 = (const float*)d_in[0];
  const float* x2 = (const float*)d_in[1];
  const float* Wk = (const float*)d_in[2];
  const float* bk = (const float*)d_in[3];
  const float* Wv = (const float*)d_in[4];
  const float* bv = (const float*)d_in[5];
  const float* Wp = (const float*)d_in[6];
  const float* bp = (const float*)d_in[7];
  float* P = (float*)d_ws;  // 2 * 8*64*84*84 floats = 28.9 MB
  float* out = (float*)d_out;

  k1_fused<<<dim3(2 * BB * SPP), dim3(256), 0, stream>>>(x1, x2, Wk, bk, Wv, bv, Wp, P);
  k2_merge<<<dim3(BB * HH), dim3(256), 0, stream>>>(P, bp, out);
}

// Round 3
// 414.282 us; speedup vs baseline: 1.5787x; 1.5787x over previous
//
#include <hip/hip_runtime.h>

// B=8, H=W=256, I_DIM=64, K_DIM=64 (hd_k=32), V_DIM=32 (hd_v=16), O_DIM=64
// NH=2, unfold: p=7, stride=21, dilation=4, npw=12 -> S=144 patches
// Sampled grid 84x84; each sampled pixel belongs to exactly ONE patch.
#define BB 8
#define HH 256
#define CIN 64
#define NPW 12
#define SPP 144
#define PP 49
#define PDIM 7
#define STRIDE 21
#define DIL 4
#define NS 84
#define HDK 32
#define HDV 16

static __device__ __forceinline__ unsigned short f2bf(float f) {
  union { float f; unsigned u; } v; v.f = f;
  unsigned r = (v.u + 0x7fffu + ((v.u >> 16) & 1u)) >> 16;
  return (unsigned short)r;
}
static __device__ __forceinline__ float bf2f(unsigned short h) {
  union { unsigned u; float f; } v; v.u = ((unsigned)h) << 16;
  return v.f;
}

// ---------------------------------------------------------------------------
// Kernel 1: one block per (b, patch), BOTH heads. Gather x1/x2 once, project
// K1/K2/V1/V2 (bf16 in LDS), per-head 49x49 dual softmax attention, collect
// all 64 o-channels, FULL 64x64 out-projection, write P[b][oc][84][84].
// Natural block order (no swizzle) so neighboring-pj blocks merge partial
// cache-line writes in L2 (R1 measured: zero write amplification).
// ---------------------------------------------------------------------------
__global__ __launch_bounds__(256, 3) void k1_fused(
    const float* __restrict__ x1, const float* __restrict__ x2,
    const float* __restrict__ Wk, const float* __restrict__ bk,
    const float* __restrict__ Wv, const float* __restrict__ bv,
    const float* __restrict__ Wp, float* __restrict__ P)
{
  // kv rows (bf16): 0..63 K1 (ch=row), 64..127 K2, 128..159 V1, 160..191 V2
  __shared__ unsigned short kv[192][52];                  // 19968 B
  __shared__ union UU {
    float xs[2][CIN][50];                                 // 25600 B (ph 0-1)
    struct {                                              // ph 2+
      float A1[49][50];                                   // 9800
      float A2[49][50];                                   // 9800
      float rmax[49], rsum[49], cmax[49], csum[49];       // 784
      float O[64][50];                                    // 12800 (row = o-ch)
    } a;
  } u;                                                    // union = 33184 B

  const int tid = threadIdx.x;
  const int blk = blockIdx.x;
  const int b  = blk / SPP;
  const int s  = blk % SPP;
  const int pi = s / NPW, pj = s % NPW;
  const int h0 = pi * STRIDE, w0 = pj * STRIDE;

  // ---- phase 0: gather x tiles into LDS ----
  for (int i = tid; i < 2 * CIN * PP; i += 256) {
    int src = i / (CIN * PP);
    int r = i - src * (CIN * PP);
    int c = r / PP, t = r - c * PP;
    int ph = t / PDIM, pw = t - ph * PDIM;
    const float* xp = src ? x2 : x1;
    u.xs[src][c][t] =
        xp[(((size_t)b * CIN + c) * HH + (h0 + ph * DIL)) * HH + (w0 + pw * DIL)];
  }
  __syncthreads();

  // ---- phase 1: projections 192 rows x 49 px, 4x4 register tiles ----
  for (int task = tid; task < 48 * 13; task += 256) {
    int g = task / 13, tg = task % 13;
    int row0 = g * 4, t0 = tg * 4;
    int tc[4];
    #pragma unroll
    for (int j = 0; j < 4; j++) tc[j] = min(t0 + j, PP - 1);
    int src = (row0 < 64) ? 0 : (row0 < 128 ? 1 : (row0 < 160 ? 0 : 1));
    const float* wbase;
    float bias[4];
    if (row0 < 128) {
      wbase = Wk + row0 * 64;
      #pragma unroll
      for (int i = 0; i < 4; i++) bias[i] = bk[row0 + i];
    } else {
      wbase = Wv + (row0 - 128) * 64;
      #pragma unroll
      for (int i = 0; i < 4; i++) bias[i] = bv[row0 - 128 + i];
    }
    const float* xsrc = &u.xs[src][0][0];
    float acc[4][4];
    #pragma unroll
    for (int i = 0; i < 4; i++)
      #pragma unroll
      for (int j = 0; j < 4; j++) acc[i][j] = 0.f;
    for (int c = 0; c < 64; c++) {
      float wv0 = wbase[c], wv1 = wbase[64 + c], wv2 = wbase[128 + c], wv3 = wbase[192 + c];
      #pragma unroll
      for (int j = 0; j < 4; j++) {
        float xv = xsrc[c * 50 + tc[j]];
        acc[0][j] += wv0 * xv; acc[1][j] += wv1 * xv;
        acc[2][j] += wv2 * xv; acc[3][j] += wv3 * xv;
      }
    }
    #pragma unroll
    for (int i = 0; i < 4; i++)
      #pragma unroll
      for (int j = 0; j < 4; j++)
        if (t0 + j < PP) kv[row0 + i][t0 + j] = f2bf(acc[i][j] + bias[i]);
  }
  __syncthreads();  // xs dead; union becomes A1/A2/stats/O

  const float scale = 0.17677669529663687f;  // 1/sqrt(32)

  for (int n = 0; n < 2; n++) {
    // ---- phase 2: kk[x][y] = scale * sum_d K1[n*32+d][x]*K2[n*32+d][y] ----
    for (int task = tid; task < 13 * 13; task += 256) {
      int xg = task / 13, yg = task % 13;
      int x0 = xg * 4, y0 = yg * 4;
      int xc[4], yc[4];
      #pragma unroll
      for (int j = 0; j < 4; j++) { xc[j] = min(x0 + j, 48); yc[j] = min(y0 + j, 48); }
      float acc[4][4];
      #pragma unroll
      for (int i = 0; i < 4; i++)
        #pragma unroll
        for (int j = 0; j < 4; j++) acc[i][j] = 0.f;
      for (int d = 0; d < HDK; d++) {
        const unsigned short* k1r = kv[n * HDK + d];
        const unsigned short* k2r = kv[64 + n * HDK + d];
        float a0 = bf2f(k1r[xc[0]]), a1v = bf2f(k1r[xc[1]]);
        float a2v = bf2f(k1r[xc[2]]), a3v = bf2f(k1r[xc[3]]);
        float b0 = bf2f(k2r[yc[0]]), b1v = bf2f(k2r[yc[1]]);
        float b2v = bf2f(k2r[yc[2]]), b3v = bf2f(k2r[yc[3]]);
        acc[0][0] += a0 * b0;  acc[0][1] += a0 * b1v;  acc[0][2] += a0 * b2v;  acc[0][3] += a0 * b3v;
        acc[1][0] += a1v * b0; acc[1][1] += a1v * b1v; acc[1][2] += a1v * b2v; acc[1][3] += a1v * b3v;
        acc[2][0] += a2v * b0; acc[2][1] += a2v * b1v; acc[2][2] += a2v * b2v; acc[2][3] += a2v * b3v;
        acc[3][0] += a3v * b0; acc[3][1] += a3v * b1v; acc[3][2] += a3v * b2v; acc[3][3] += a3v * b3v;
      }
      #pragma unroll
      for (int i = 0; i < 4; i++)
        if (x0 + i < 49)
          #pragma unroll
          for (int j = 0; j < 4; j++)
            if (y0 + j < 49) u.a.A1[x0 + i][y0 + j] = acc[i][j] * scale;
    }
    __syncthreads();

    // ---- phase 3: softmax stats (cols for a1, rows for a2) ----
    if (tid < 98) {
      int isRow = tid >= 49;
      int j = tid - (isRow ? 49 : 0);
      float m = -1e30f;
      for (int k = 0; k < 49; k++) {
        float v = isRow ? u.a.A1[j][k] : u.a.A1[k][j];
        m = fmaxf(m, v);
      }
      float sm = 0.f;
      for (int k = 0; k < 49; k++) {
        float v = isRow ? u.a.A1[j][k] : u.a.A1[k][j];
        sm += __expf(v - m);
      }
      if (isRow) { u.a.rmax[j] = m; u.a.rsum[j] = 1.0f / sm; }
      else       { u.a.cmax[j] = m; u.a.csum[j] = 1.0f / sm; }
    }
    __syncthreads();

    // ---- phase 4: A2 = row softmax, A1 = col softmax (in place) ----
    for (int i = tid; i < 49 * 49; i += 256) {
      int x = i / 49, y = i - x * 49;
      float v = u.a.A1[x][y];
      u.a.A2[x][y] = __expf(v - u.a.rmax[x]) * u.a.rsum[x];
      u.a.A1[x][y] = __expf(v - u.a.cmax[y]) * u.a.csum[y];
    }
    __syncthreads();

    // ---- phase 5: o1[d][y] = sum_x A1[x][y]*V1[d][x] -> O[n*16+d]
    //              o2[d][x] = sum_y A2[x][y]*V2[d][y] -> O[32+n*16+d]
    for (int task = tid; task < 2 * 4 * 13; task += 256) {
      int which = task / 52;
      int r = task - which * 52;
      int dg = r / 13, tg = r % 13;
      int d0 = dg * 4, t0 = tg * 4;
      int tc[4];
      #pragma unroll
      for (int j = 0; j < 4; j++) tc[j] = min(t0 + j, 48);
      float acc[4][4];
      #pragma unroll
      for (int i = 0; i < 4; i++)
        #pragma unroll
        for (int j = 0; j < 4; j++) acc[i][j] = 0.f;
      if (which == 0) {
        for (int x = 0; x < 49; x++) {
          float a0 = u.a.A1[x][tc[0]], a1v = u.a.A1[x][tc[1]];
          float a2v = u.a.A1[x][tc[2]], a3v = u.a.A1[x][tc[3]];
          #pragma unroll
          for (int i = 0; i < 4; i++) {
            float vv = bf2f(kv[128 + n * HDV + d0 + i][x]);
            acc[i][0] += vv * a0; acc[i][1] += vv * a1v;
            acc[i][2] += vv * a2v; acc[i][3] += vv * a3v;
          }
        }
      } else {
        for (int y = 0; y < 49; y++) {
          float a0 = u.a.A2[tc[0]][y], a1v = u.a.A2[tc[1]][y];
          float a2v = u.a.A2[tc[2]][y], a3v = u.a.A2[tc[3]][y];
          #pragma unroll
          for (int i = 0; i < 4; i++) {
            float vv = bf2f(kv[160 + n * HDV + d0 + i][y]);
            acc[i][0] += vv * a0; acc[i][1] += vv * a1v;
            acc[i][2] += vv * a2v; acc[i][3] += vv * a3v;
          }
        }
      }
      #pragma unroll
      for (int i = 0; i < 4; i++)
        #pragma unroll
        for (int j = 0; j < 4; j++)
          if (t0 + j < 49) u.a.O[which * 32 + n * HDV + d0 + i][t0 + j] = acc[i][j];
    }
    __syncthreads();  // A buffers reused next head; O persists (union struct)
  }

  // ---- phase 6: full out-proj. P[oc][t] = sum_l Wp[oc][l] * O[l][t]  (ch==l)
  for (int task = tid; task < 16 * 13; task += 256) {
    int ocg = task / 13, tg = task % 13;
    int oc0 = ocg * 4, t0 = tg * 4;
    int tc[4];
    #pragma unroll
    for (int j = 0; j < 4; j++) tc[j] = min(t0 + j, 48);
    float acc[4][4];
    #pragma unroll
    for (int i = 0; i < 4; i++)
      #pragma unroll
      for (int j = 0; j < 4; j++) acc[i][j] = 0.f;
    #pragma unroll 4
    for (int l = 0; l < 64; l++) {
      float w0 = Wp[(oc0 + 0) * 64 + l];
      float w1 = Wp[(oc0 + 1) * 64 + l];
      float w2 = Wp[(oc0 + 2) * 64 + l];
      float w3 = Wp[(oc0 + 3) * 64 + l];
      float o0 = u.a.O[l][tc[0]], o1v = u.a.O[l][tc[1]];
      float o2v = u.a.O[l][tc[2]], o3v = u.a.O[l][tc[3]];
      acc[0][0] += w0 * o0; acc[0][1] += w0 * o1v; acc[0][2] += w0 * o2v; acc[0][3] += w0 * o3v;
      acc[1][0] += w1 * o0; acc[1][1] += w1 * o1v; acc[1][2] += w1 * o2v; acc[1][3] += w1 * o3v;
      acc[2][0] += w2 * o0; acc[2][1] += w2 * o1v; acc[2][2] += w2 * o2v; acc[2][3] += w2 * o3v;
      acc[3][0] += w3 * o0; acc[3][1] += w3 * o1v; acc[3][2] += w3 * o2v; acc[3][3] += w3 * o3v;
    }
    #pragma unroll
    for (int i = 0; i < 4; i++) {
      #pragma unroll
      for (int j = 0; j < 4; j++) {
        int t = t0 + j;
        if (t < 49) {
          int ph = t / 7, pw = t - ph * 7;
          P[(((size_t)b * 64 + (oc0 + i)) * NS + (pi * 7 + ph)) * NS + (pj * 7 + pw)] =
              acc[i][j];
        }
      }
    }
  }
}

// ---------------------------------------------------------------------------
// Kernel 2: merge. out[b][oc][h][w] = bp[oc] + (sampled ? P : 0). float4.
// ---------------------------------------------------------------------------
__global__ __launch_bounds__(256) void k2_merge(
    const float* __restrict__ P, const float* __restrict__ bp,
    float* __restrict__ out)
{
  __shared__ float bps[64];
  __shared__ int wsmap[256];
  const int tid = threadIdx.x;
  const int b = blockIdx.x / HH, h = blockIdx.x % HH;
  if (tid < 64) bps[tid] = bp[tid];
  {
    int w = tid, wsv = -1;
    for (int pj = 0; pj < NPW; pj++) {
      int r = w - pj * STRIDE;
      if (r >= 0 && r <= (PDIM - 1) * DIL && (r % DIL) == 0) { wsv = pj * PDIM + r / DIL; break; }
    }
    wsmap[tid] = wsv;
  }
  int hs = -1;
  for (int pi = 0; pi < NPW; pi++) {
    int r = h - pi * STRIDE;
    if (r >= 0 && r <= (PDIM - 1) * DIL && (r % DIL) == 0) { hs = pi * PDIM + r / DIL; break; }
  }
  __syncthreads();

  const int wq = tid & 63;   // float4 column
  const int ocq = tid >> 6;  // 0..3
  float4* out4 = (float4*)out;

  if (hs < 0) {
    #pragma unroll 4
    for (int oc = ocq; oc < 64; oc += 4) {
      float bv = bps[oc];
      out4[(((size_t)b * 64 + oc) * HH + h) * 64 + wq] = make_float4(bv, bv, bv, bv);
    }
    return;
  }
  const int ws0 = wsmap[wq * 4 + 0], ws1 = wsmap[wq * 4 + 1];
  const int ws2 = wsmap[wq * 4 + 2], ws3 = wsmap[wq * 4 + 3];
  #pragma unroll 4
  for (int oc = ocq; oc < 64; oc += 4) {
    float bv = bps[oc];
    size_t rbase = (((size_t)b * 64 + oc) * NS + hs) * NS;
    float4 v = make_float4(bv, bv, bv, bv);
    if (ws0 >= 0) v.x += P[rbase + ws0];
    if (ws1 >= 0) v.y += P[rbase + ws1];
    if (ws2 >= 0) v.z += P[rbase + ws2];
    if (ws3 >= 0) v.w += P[rbase + ws3];
    out4[(((size_t)b * 64 + oc) * HH + h) * 64 + wq] = v;
  }
}

extern "C" void kernel_launch(void* const* d_in, const int* in_sizes, int n_in,
                              void* d_out, int out_size, void* d_ws, size_t ws_size,
                              hipStream_t stream) {
  const float* x1 = (const float*)d_in[0];
  const float* x2 = (const float*)d_in[1];
  const float* Wk = (const float*)d_in[2];
  const float* bk = (const float*)d_in[3];
  const float* Wv = (const float*)d_in[4];
  const float* bv = (const float*)d_in[5];
  const float* Wp = (const float*)d_in[6];
  const float* bp = (const float*)d_in[7];
  float* P = (float*)d_ws;  // 8*64*84*84 floats = 14.45 MB
  float* out = (float*)d_out;

  k1_fused<<<dim3(BB * SPP), dim3(256), 0, stream>>>(x1, x2, Wk, bk, Wv, bv, Wp, P);
  k2_merge<<<dim3(BB * HH), dim3(256), 0, stream>>>(P, bp, out);
}

// Round 4
// 407.352 us; speedup vs baseline: 1.6055x; 1.0170x over previous
//
#include <hip/hip_runtime.h>

// B=8, H=W=256, I_DIM=64, K_DIM=64 (hd_k=32), V_DIM=32 (hd_v=16), O_DIM=64
// NH=2, unfold: p=7, stride=21, dilation=4, npw=12 -> S=144 patches
// Sampled grid 84x84; each sampled pixel belongs to exactly ONE patch.
#define BB 8
#define HH 256
#define CIN 64
#define NPW 12
#define SPP 144
#define PP 49
#define PDIM 7
#define STRIDE 21
#define DIL 4
#define NS 84
#define HDK 32
#define HDV 16
#define RS 52   // bf16 row stride (shorts): 104 B rows, 8 B-aligned ushort4 at 4k offsets

static __device__ __forceinline__ unsigned short f2bf(float f) {
  union { float f; unsigned u; } v; v.f = f;
  unsigned r = (v.u + 0x7fffu + ((v.u >> 16) & 1u)) >> 16;
  return (unsigned short)r;
}
static __device__ __forceinline__ float bf2f(unsigned short h) {
  union { unsigned u; float f; } v; v.u = ((unsigned)h) << 16;
  return v.f;
}

// ---------------------------------------------------------------------------
// Kernel 1: one block per (b, patch), both heads IN PARALLEL per phase.
// 5 barriers total. bf16 LDS throughout -> 37.5 KB -> 4 blocks/CU.
// Phases: 0 gather(xs) | 1 proj(kv) | 2 logits(kkb) | 3 softmax stats |
//         5 AV with inline exp (O) | 6 out-proj -> P[b][oc][84][84].
// ---------------------------------------------------------------------------
__global__ __launch_bounds__(256, 4) void k1_fused(
    const float* __restrict__ x1, const float* __restrict__ x2,
    const float* __restrict__ Wk, const float* __restrict__ bk,
    const float* __restrict__ Wv, const float* __restrict__ bv,
    const float* __restrict__ Wp, float* __restrict__ P)
{
  // kv rows (bf16): 0..63 K1 (ch=row), 64..127 K2, 128..159 V1, 160..191 V2
  __shared__ unsigned short kv[192][RS];                  // 19968 B
  __shared__ union UU {
    unsigned short xs[2][CIN][RS];                        // 13312 B (ph 0-1)
    struct {                                              // ph 2+
      unsigned short kkb[2][49][RS];                      // 10192 (bf16 logits)
      unsigned short O[64][RS];                           // 6656  (bf16 o-ch)
      float cmax[2][49], csum[2][49];                     // 1568 total stats
      float rmax[2][49], rsum[2][49];
    } a;
  } u;                                                    // union = 18416 B

  const int tid = threadIdx.x;
  const int blk = blockIdx.x;
  const int b  = blk / SPP;
  const int s  = blk % SPP;
  const int pi = s / NPW, pj = s % NPW;
  const int h0 = pi * STRIDE, w0 = pj * STRIDE;

  // ---- phase 0: gather x tiles into LDS (bf16) ----
  for (int i = tid; i < 2 * CIN * PP; i += 256) {
    int src = i / (CIN * PP);
    int r = i - src * (CIN * PP);
    int c = r / PP, t = r - c * PP;
    int ph = t / PDIM, pw = t - ph * PDIM;
    const float* xp = src ? x2 : x1;
    float v = xp[(((size_t)b * CIN + c) * HH + (h0 + ph * DIL)) * HH + (w0 + pw * DIL)];
    u.xs[src][c][t] = f2bf(v);
  }
  __syncthreads();

  // ---- phase 1: projections 192 rows x 49 px, 4x4 register tiles ----
  for (int task = tid; task < 48 * 13; task += 256) {
    int g = task / 13, tg = task % 13;
    int row0 = g * 4, t0 = tg * 4;
    int src = (row0 < 64) ? 0 : (row0 < 128 ? 1 : (row0 < 160 ? 0 : 1));
    const float* wbase;
    float bias[4];
    if (row0 < 128) {
      wbase = Wk + row0 * 64;
      #pragma unroll
      for (int i = 0; i < 4; i++) bias[i] = bk[row0 + i];
    } else {
      wbase = Wv + (row0 - 128) * 64;
      #pragma unroll
      for (int i = 0; i < 4; i++) bias[i] = bv[row0 - 128 + i];
    }
    const unsigned short* xsrc = &u.xs[src][0][0];
    float acc[4][4];
    #pragma unroll
    for (int i = 0; i < 4; i++)
      #pragma unroll
      for (int j = 0; j < 4; j++) acc[i][j] = 0.f;
    for (int c = 0; c < 64; c++) {
      float wv0 = wbase[c], wv1 = wbase[64 + c], wv2 = wbase[128 + c], wv3 = wbase[192 + c];
      ushort4 x4 = *(const ushort4*)&xsrc[c * RS + t0];   // 8B-aligned; pad cols safe
      float xv[4] = { bf2f(x4.x), bf2f(x4.y), bf2f(x4.z), bf2f(x4.w) };
      #pragma unroll
      for (int j = 0; j < 4; j++) {
        acc[0][j] += wv0 * xv[j]; acc[1][j] += wv1 * xv[j];
        acc[2][j] += wv2 * xv[j]; acc[3][j] += wv3 * xv[j];
      }
    }
    #pragma unroll
    for (int i = 0; i < 4; i++)
      #pragma unroll
      for (int j = 0; j < 4; j++)
        if (t0 + j < PP) kv[row0 + i][t0 + j] = f2bf(acc[i][j] + bias[i]);
  }
  __syncthreads();  // xs dead; union becomes kkb/O/stats

  const float scale = 0.17677669529663687f;  // 1/sqrt(32)

  // ---- phase 2: logits kkb[n][x][y] = bf16(scale * sum_d K1*K2), both heads
  // 2 heads x 13 xg x 7 yg = 182 tasks, 4x7 tiles (y tiles cover 49 exactly)
  if (tid < 182) {
    int n = tid / 91;
    int r = tid % 91;
    int xg = r / 7, yg = r % 7;
    int x0 = xg * 4, y0 = yg * 7;
    float acc[4][7];
    #pragma unroll
    for (int i = 0; i < 4; i++)
      #pragma unroll
      for (int j = 0; j < 7; j++) acc[i][j] = 0.f;
    for (int d = 0; d < HDK; d++) {
      const unsigned short* k1r = kv[n * HDK + d];
      const unsigned short* k2r = kv[64 + n * HDK + d];
      ushort4 a4 = *(const ushort4*)&k1r[x0];             // pad cols safe (guarded store)
      float av[4] = { bf2f(a4.x), bf2f(a4.y), bf2f(a4.z), bf2f(a4.w) };
      float bvv[7];
      #pragma unroll
      for (int j = 0; j < 7; j++) bvv[j] = bf2f(k2r[y0 + j]);
      #pragma unroll
      for (int i = 0; i < 4; i++)
        #pragma unroll
        for (int j = 0; j < 7; j++) acc[i][j] += av[i] * bvv[j];
    }
    #pragma unroll
    for (int i = 0; i < 4; i++)
      if (x0 + i < 49)
        #pragma unroll
        for (int j = 0; j < 7; j++)
          u.a.kkb[n][x0 + i][y0 + j] = f2bf(acc[i][j] * scale);
  }
  __syncthreads();

  // ---- phase 3: softmax stats, both heads: 2 x (49 col + 49 row) = 196 thr
  if (tid < 196) {
    int n = tid / 98;
    int r = tid % 98;
    int isRow = r >= 49;
    int j = r - (isRow ? 49 : 0);
    float m = -1e30f;
    for (int k = 0; k < 49; k++) {
      float v = bf2f(isRow ? u.a.kkb[n][j][k] : u.a.kkb[n][k][j]);
      m = fmaxf(m, v);
    }
    float sm = 0.f;
    for (int k = 0; k < 49; k++) {
      float v = bf2f(isRow ? u.a.kkb[n][j][k] : u.a.kkb[n][k][j]);
      sm += __expf(v - m);
    }
    if (isRow) { u.a.rmax[n][j] = m; u.a.rsum[n][j] = 1.0f / sm; }
    else       { u.a.cmax[n][j] = m; u.a.csum[n][j] = 1.0f / sm; }
  }
  __syncthreads();

  // ---- phase 5: AV with inline exp, both heads+sides: 2n x 2side x 4dg x 13tg
  // side 0: o1[d][t] = csum[t] * sum_x exp(kk[x][t]-cmax[t]) * V1[d][x] -> O[n*16+d]
  // side 1: o2[d][t] = rsum[t] * sum_y exp(kk[t][y]-rmax[t]) * V2[d][y] -> O[32+n*16+d]
  if (tid < 208) {
    int n = tid / 104;
    int r = tid % 104;
    int side = r / 52;
    int r2 = r % 52;
    int dg = r2 / 13, tg = r2 % 13;
    int d0 = dg * 4, t0 = tg * 4;
    int tc[4];
    #pragma unroll
    for (int j = 0; j < 4; j++) tc[j] = min(t0 + j, 48);
    float acc[4][4];
    #pragma unroll
    for (int i = 0; i < 4; i++)
      #pragma unroll
      for (int j = 0; j < 4; j++) acc[i][j] = 0.f;
    if (side == 0) {
      float cm[4];
      #pragma unroll
      for (int j = 0; j < 4; j++) cm[j] = u.a.cmax[n][tc[j]];
      for (int x = 0; x < 49; x++) {
        ushort4 k4 = *(const ushort4*)&u.a.kkb[n][x][t0];  // pad cols safe
        float e[4] = { __expf(bf2f(k4.x) - cm[0]), __expf(bf2f(k4.y) - cm[1]),
                       __expf(bf2f(k4.z) - cm[2]), __expf(bf2f(k4.w) - cm[3]) };
        #pragma unroll
        for (int i = 0; i < 4; i++) {
          float vv = bf2f(kv[128 + n * HDV + d0 + i][x]);
          acc[i][0] += vv * e[0]; acc[i][1] += vv * e[1];
          acc[i][2] += vv * e[2]; acc[i][3] += vv * e[3];
        }
      }
      #pragma unroll
      for (int i = 0; i < 4; i++)
        #pragma unroll
        for (int j = 0; j < 4; j++)
          if (t0 + j < 49)
            u.a.O[n * HDV + d0 + i][t0 + j] = f2bf(acc[i][j] * u.a.csum[n][t0 + j]);
    } else {
      float rm[4];
      #pragma unroll
      for (int j = 0; j < 4; j++) rm[j] = u.a.rmax[n][tc[j]];
      for (int y = 0; y < 49; y++) {
        float e[4];
        #pragma unroll
        for (int j = 0; j < 4; j++)
          e[j] = __expf(bf2f(u.a.kkb[n][tc[j]][y]) - rm[j]);
        #pragma unroll
        for (int i = 0; i < 4; i++) {
          float vv = bf2f(kv[160 + n * HDV + d0 + i][y]);
          acc[i][0] += vv * e[0]; acc[i][1] += vv * e[1];
          acc[i][2] += vv * e[2]; acc[i][3] += vv * e[3];
        }
      }
      #pragma unroll
      for (int i = 0; i < 4; i++)
        #pragma unroll
        for (int j = 0; j < 4; j++)
          if (t0 + j < 49)
            u.a.O[32 + n * HDV + d0 + i][t0 + j] = f2bf(acc[i][j] * u.a.rsum[n][t0 + j]);
    }
  }
  __syncthreads();

  // ---- phase 6: full out-proj. P[oc][t] = sum_l Wp[oc][l] * O[l][t]
  if (tid < 208) {
    int ocg = tid / 13, tg = tid % 13;   // 16 x 13
    int oc0 = ocg * 4, t0 = tg * 4;
    float acc[4][4];
    #pragma unroll
    for (int i = 0; i < 4; i++)
      #pragma unroll
      for (int j = 0; j < 4; j++) acc[i][j] = 0.f;
    #pragma unroll 4
    for (int l = 0; l < 64; l++) {
      float w0 = Wp[(oc0 + 0) * 64 + l];
      float w1 = Wp[(oc0 + 1) * 64 + l];
      float w2 = Wp[(oc0 + 2) * 64 + l];
      float w3 = Wp[(oc0 + 3) * 64 + l];
      ushort4 o4 = *(const ushort4*)&u.a.O[l][t0];        // pad cols safe
      float ov[4] = { bf2f(o4.x), bf2f(o4.y), bf2f(o4.z), bf2f(o4.w) };
      #pragma unroll
      for (int j = 0; j < 4; j++) {
        acc[0][j] += w0 * ov[j]; acc[1][j] += w1 * ov[j];
        acc[2][j] += w2 * ov[j]; acc[3][j] += w3 * ov[j];
      }
    }
    #pragma unroll
    for (int i = 0; i < 4; i++) {
      #pragma unroll
      for (int j = 0; j < 4; j++) {
        int t = t0 + j;
        if (t < 49) {
          int ph = t / 7, pw = t - ph * 7;
          P[(((size_t)b * 64 + (oc0 + i)) * NS + (pi * 7 + ph)) * NS + (pj * 7 + pw)] =
              acc[i][j];
        }
      }
    }
  }
}

// ---------------------------------------------------------------------------
// Kernel 2: merge. out[b][oc][h][w] = bp[oc] + (sampled ? P : 0). float4.
// ---------------------------------------------------------------------------
__global__ __launch_bounds__(256) void k2_merge(
    const float* __restrict__ P, const float* __restrict__ bp,
    float* __restrict__ out)
{
  __shared__ float bps[64];
  __shared__ int wsmap[256];
  const int tid = threadIdx.x;
  const int b = blockIdx.x / HH, h = blockIdx.x % HH;
  if (tid < 64) bps[tid] = bp[tid];
  {
    int w = tid, wsv = -1;
    for (int pj = 0; pj < NPW; pj++) {
      int r = w - pj * STRIDE;
      if (r >= 0 && r <= (PDIM - 1) * DIL && (r % DIL) == 0) { wsv = pj * PDIM + r / DIL; break; }
    }
    wsmap[tid] = wsv;
  }
  int hs = -1;
  for (int pi = 0; pi < NPW; pi++) {
    int r = h - pi * STRIDE;
    if (r >= 0 && r <= (PDIM - 1) * DIL && (r % DIL) == 0) { hs = pi * PDIM + r / DIL; break; }
  }
  __syncthreads();

  const int wq = tid & 63;   // float4 column
  const int ocq = tid >> 6;  // 0..3
  float4* out4 = (float4*)out;

  if (hs < 0) {
    #pragma unroll 4
    for (int oc = ocq; oc < 64; oc += 4) {
      float bv = bps[oc];
      out4[(((size_t)b * 64 + oc) * HH + h) * 64 + wq] = make_float4(bv, bv, bv, bv);
    }
    return;
  }
  const int ws0 = wsmap[wq * 4 + 0], ws1 = wsmap[wq * 4 + 1];
  const int ws2 = wsmap[wq * 4 + 2], ws3 = wsmap[wq * 4 + 3];
  #pragma unroll 4
  for (int oc = ocq; oc < 64; oc += 4) {
    float bv = bps[oc];
    size_t rbase = (((size_t)b * 64 + oc) * NS + hs) * NS;
    float4 v = make_float4(bv, bv, bv, bv);
    if (ws0 >= 0) v.x += P[rbase + ws0];
    if (ws1 >= 0) v.y += P[rbase + ws1];
    if (ws2 >= 0) v.z += P[rbase + ws2];
    if (ws3 >= 0) v.w += P[rbase + ws3];
    out4[(((size_t)b * 64 + oc) * HH + h) * 64 + wq] = v;
  }
}

extern "C" void kernel_launch(void* const* d_in, const int* in_sizes, int n_in,
                              void* d_out, int out_size, void* d_ws, size_t ws_size,
                              hipStream_t stream) {
  const float* x1 = (const float*)d_in[0];
  const float* x2 = (const float*)d_in[1];
  const float* Wk = (const float*)d_in[2];
  const float* bk = (const float*)d_in[3];
  const float* Wv = (const float*)d_in[4];
  const float* bv = (const float*)d_in[5];
  const float* Wp = (const float*)d_in[6];
  const float* bp = (const float*)d_in[7];
  float* P = (float*)d_ws;  // 8*64*84*84 floats = 14.45 MB
  float* out = (float*)d_out;

  k1_fused<<<dim3(BB * SPP), dim3(256), 0, stream>>>(x1, x2, Wk, bk, Wv, bv, Wp, P);
  k2_merge<<<dim3(BB * HH), dim3(256), 0, stream>>>(P, bp, out);
}